// Round 1
// baseline (214.686 us; speedup 1.0000x reference)
//
#include <hip/hip_runtime.h>
#include <hip/hip_bf16.h>
#include <stdint.h>

typedef __bf16 bf16;
typedef __bf16 bf16x8 __attribute__((ext_vector_type(8)));
typedef __bf16 bf16x4 __attribute__((ext_vector_type(4)));
typedef float f32x4 __attribute__((ext_vector_type(4)));

#define GAS __attribute__((address_space(1)))
#define LAS __attribute__((address_space(3)))

#define NROIS 1000
#define DEPTH 256
#define CIN 320
#define KDIM 15680      // 320*49
#define MPAD 1024
#define TABS 120        // floats per roi in table

// ws byte offsets
#define OFF_TAB  0
#define OFF_A    524288ULL
#define OFF_W1   (OFF_A + 32112640ULL)     // 1024*15680*2
#define OFF_W2   (OFF_W1 + 32112640ULL)
#define OFF_PART (OFF_W2 + 2097152ULL)
#define OFF_X1B  (OFF_PART + 33554432ULL)  // 8 * 1024*1024*4
#define OFF_X2   (OFF_X1B + 2097152ULL)

// ---------------- per-ROI interpolation tables ----------------
__global__ void k_roi_setup(const float* __restrict__ rois, float* __restrict__ tab) {
    int n = blockIdx.x * 256 + threadIdx.x;
    if (n >= NROIS) return;
    float y1 = rois[n*4+0], x1 = rois[n*4+1], y2 = rois[n*4+2], x2 = rois[n*4+3];
    float h = __fsub_rn(y2, y1), w = __fsub_rn(x2, x1);
    // roi_level = clip(round(4 + log(sqrt(h*w)/(224/640))/log(2)), 2, 5)
    float rl = 4.0f + logf(sqrtf(h * w) / (224.0f / 640.0f)) / logf(2.0f);
    int lvl = (int)rintf(rl);
    lvl = min(5, max(2, lvl));
    float* t = tab + (size_t)n * TABS;
    t[112] = (float)lvl;
    int Hs0 = 160 >> (lvl - 2);
    for (int g = 0; g < 2; g++) {
        int H = g ? 160 : Hs0;
        float* tg = t + g * 56;
        float fH = (float)(H - 1);
        // y axis
        float a = __fmul_rn(y1, fH);
        float s = __fdiv_rn(__fmul_rn(h, fH), 6.0f);
        for (int i = 0; i < 7; i++) {
            float iny = __fadd_rn(a, __fmul_rn((float)i, s));
            float tp = floorf(iny), bt = ceilf(iny);
            tg[i]      = (float)min(H-1, max(0, (int)tp));
            tg[7 + i]  = (float)min(H-1, max(0, (int)bt));
            tg[14 + i] = iny - tp;
            tg[21 + i] = (iny >= 0.0f && iny <= fH) ? 1.0f : 0.0f;
        }
        // x axis
        a = __fmul_rn(x1, fH);
        s = __fdiv_rn(__fmul_rn(w, fH), 6.0f);
        for (int j = 0; j < 7; j++) {
            float inx = __fadd_rn(a, __fmul_rn((float)j, s));
            float lf = floorf(inx), rt = ceilf(inx);
            tg[28 + j] = (float)min(H-1, max(0, (int)lf));
            tg[35 + j] = (float)min(H-1, max(0, (int)rt));
            tg[42 + j] = inx - lf;
            tg[49 + j] = (inx >= 0.0f && inx <= fH) ? 1.0f : 0.0f;
        }
    }
}

// ---------------- weight f32 -> bf16 convert ----------------
__global__ void k_convert(const float* __restrict__ w1, const float* __restrict__ w2,
                          bf16* __restrict__ W1b, bf16* __restrict__ W2b) {
    int idx = blockIdx.x * 256 + threadIdx.x;     // one float4 per thread
    const int n1 = 16056320 / 4;
    f32x4 v; bf16* dst;
    if (idx < n1) { v = ((const f32x4*)w1)[idx]; dst = W1b + (size_t)idx * 4; }
    else { int k = idx - n1; v = ((const f32x4*)w2)[k]; dst = W2b + (size_t)k * 4; }
    bf16x4 o;
    o[0] = (bf16)v[0]; o[1] = (bf16)v[1]; o[2] = (bf16)v[2]; o[3] = (bf16)v[3];
    *(bf16x4*)dst = o;
}

// ---------------- crop_and_resize: write roi_features f32 + bf16 A ----------------
__global__ void k_crop(const float* __restrict__ p2, const float* __restrict__ p3,
                       const float* __restrict__ p4, const float* __restrict__ p5,
                       const float* __restrict__ ranges, const float* __restrict__ tab,
                       float* __restrict__ out_rf, bf16* __restrict__ A) {
    int idx = blockIdx.x * 256 + threadIdx.x;     // exactly 1024*15680 threads
    if (idx >= NROIS * KDIM) { A[idx] = (bf16)0.0f; return; }   // zero pad rows
    int pos = idx % 49;
    int t49 = idx / 49;
    int c = t49 % CIN;
    int n = t49 / CIN;
    int i = pos / 7, j = pos % 7;
    const float* tb = tab + (size_t)n * TABS;
    int lvl = (int)tb[112];
    const float* t = tb + ((c < DEPTH) ? 0 : 56);
    const float* fm; int H;
    if (c < DEPTH) {
        H = 160 >> (lvl - 2);
        fm = (lvl == 2) ? p2 : (lvl == 3) ? p3 : (lvl == 4) ? p4 : p5;
        fm += (size_t)c * H * H;
    } else {
        H = 160;
        fm = ranges + (size_t)(c - DEPTH) * 25600;
    }
    int ti = (int)t[i],      bi = (int)t[7 + i];
    int li = (int)t[28 + j], ri = (int)t[35 + j];
    float ly = t[14 + i], lx = t[42 + j];
    float vy = t[21 + i], vx = t[49 + j];
    const float* rt = fm + (size_t)ti * H;
    const float* rb = fm + (size_t)bi * H;
    float tl = rt[li], tr = rt[ri], bl = rb[li], br = rb[ri];
    float tv = tl + (tr - tl) * lx;
    float bv = bl + (br - bl) * lx;
    float v = tv + (bv - tv) * ly;
    if (vy * vx == 0.0f) v = 0.0f;
    out_rf[idx] = v;
    A[idx] = (bf16)v;
}

// ---------------- bf16 MFMA GEMM, C = A(MxK) * B(NxK)^T, split-K partials ----------------
__global__ __launch_bounds__(256) void k_gemm(const bf16* __restrict__ A, const bf16* __restrict__ B,
                                              float* __restrict__ part, int K,
                                              int steps_base, int steps_rem) {
    __shared__ bf16 sA[128 * 64];
    __shared__ bf16 sB[128 * 64];
    int tid = threadIdx.x;
    int l = tid & 63, w = tid >> 6;
    int tm = blockIdx.x * 128, tn = blockIdx.y * 128;
    int z = (int)blockIdx.z;
    int s0 = z * steps_base + min(z, steps_rem);
    int ns = steps_base + (z < steps_rem ? 1 : 0);
    f32x4 acc[4][4] = {};
    int rw = w * 32;
    int lr8 = l >> 3, lc8 = (l & 7) << 3;
    const bf16* Abase = A + (size_t)(tm + rw + lr8) * K + lc8;
    const bf16* Bbase = B + (size_t)(tn + rw + lr8) * K + lc8;
    int lr = l & 15, lh = l >> 4;
    int wm = (w >> 1) * 64, wn = (w & 1) * 64;

    for (int t = s0; t < s0 + ns; t++) {
        int kc = t * 64;
        #pragma unroll
        for (int q = 0; q < 4; q++) {
            __builtin_amdgcn_global_load_lds((const GAS void*)(Abase + (size_t)q * 8 * K + kc),
                                             (LAS void*)(sA + (rw + q * 8) * 64), 16, 0, 0);
            __builtin_amdgcn_global_load_lds((const GAS void*)(Bbase + (size_t)q * 8 * K + kc),
                                             (LAS void*)(sB + (rw + q * 8) * 64), 16, 0, 0);
        }
        __syncthreads();
        #pragma unroll
        for (int ks2 = 0; ks2 < 2; ks2++) {
            int kb = ks2 * 32 + lh * 8;
            bf16x8 af[4], bfr[4];
            #pragma unroll
            for (int mi = 0; mi < 4; mi++) af[mi] = *(const bf16x8*)(sA + (wm + mi * 16 + lr) * 64 + kb);
            #pragma unroll
            for (int ni = 0; ni < 4; ni++) bfr[ni] = *(const bf16x8*)(sB + (wn + ni * 16 + lr) * 64 + kb);
            #pragma unroll
            for (int mi = 0; mi < 4; mi++)
                #pragma unroll
                for (int ni = 0; ni < 4; ni++)
                    acc[mi][ni] = __builtin_amdgcn_mfma_f32_16x16x32_bf16(af[mi], bfr[ni], acc[mi][ni], 0, 0, 0);
        }
        __syncthreads();
    }
    float* pc = part + ((size_t)z << 20);
    #pragma unroll
    for (int mi = 0; mi < 4; mi++)
        #pragma unroll
        for (int ni = 0; ni < 4; ni++)
            #pragma unroll
            for (int r = 0; r < 4; r++)
                pc[(size_t)(tm + wm + mi * 16 + lh * 4 + r) * 1024 + (tn + wn + ni * 16 + lr)] = acc[mi][ni][r];
}

// ---------------- reduce split-K + bias + BN + ReLU -> bf16 (x1) ----------------
__global__ void k_reduce1(const float* __restrict__ part, const float* __restrict__ bias,
                          const float* __restrict__ gam, const float* __restrict__ bet,
                          const float* __restrict__ mu, const float* __restrict__ var,
                          bf16* __restrict__ x1b) {
    int idx = blockIdx.x * 256 + threadIdx.x;  // 262144 total
    int n = idx >> 8;
    int o = (idx & 255) << 2;
    f32x4 v = {};
    #pragma unroll
    for (int s = 0; s < 8; s++) v += *(const f32x4*)(part + ((size_t)s << 20) + (size_t)n * 1024 + o);
    f32x4 b4 = *(const f32x4*)(bias + o);
    f32x4 g4 = *(const f32x4*)(gam + o);
    f32x4 e4 = *(const f32x4*)(bet + o);
    f32x4 m4 = *(const f32x4*)(mu + o);
    f32x4 v4 = *(const f32x4*)(var + o);
    bf16x4 ov;
    #pragma unroll
    for (int e = 0; e < 4; e++) {
        float sc = g4[e] / sqrtf(v4[e] + 0.001f);
        float y = (v[e] + b4[e] - m4[e]) * sc + e4[e];
        y = fmaxf(y, 0.0f);
        if (n >= NROIS) y = 0.0f;
        ov[e] = (bf16)y;
    }
    *(bf16x4*)(x1b + (size_t)n * 1024 + o) = ov;
}

// ---------------- reduce split-K + bias + BN + ReLU -> f32 (x2) ----------------
__global__ void k_reduce2(const float* __restrict__ part, const float* __restrict__ bias,
                          const float* __restrict__ gam, const float* __restrict__ bet,
                          const float* __restrict__ mu, const float* __restrict__ var,
                          float* __restrict__ x2) {
    int idx = blockIdx.x * 256 + threadIdx.x;
    int n = idx >> 8;
    int o = (idx & 255) << 2;
    f32x4 v = {};
    #pragma unroll
    for (int s = 0; s < 4; s++) v += *(const f32x4*)(part + ((size_t)s << 20) + (size_t)n * 1024 + o);
    f32x4 b4 = *(const f32x4*)(bias + o);
    f32x4 g4 = *(const f32x4*)(gam + o);
    f32x4 e4 = *(const f32x4*)(bet + o);
    f32x4 m4 = *(const f32x4*)(mu + o);
    f32x4 v4 = *(const f32x4*)(var + o);
    f32x4 ov;
    #pragma unroll
    for (int e = 0; e < 4; e++) {
        float sc = g4[e] / sqrtf(v4[e] + 0.001f);
        float y = (v[e] + b4[e] - m4[e]) * sc + e4[e];
        ov[e] = fmaxf(y, 0.0f);
    }
    *(f32x4*)(x2 + (size_t)n * 1024 + o) = ov;
}

// ---------------- heads: logits/probs/bbox/params ----------------
__device__ __forceinline__ float wred(float v) {
    #pragma unroll
    for (int off = 32; off; off >>= 1) v += __shfl_xor(v, off);
    return v;
}

__global__ void k_heads(const float* __restrict__ x2,
                        const float* __restrict__ wc, const float* __restrict__ bc,
                        const float* __restrict__ wb, const float* __restrict__ bb,
                        const float* __restrict__ wp, const float* __restrict__ bp,
                        float* __restrict__ out) {
    int w = threadIdx.x >> 6, l = threadIdx.x & 63;
    int n = blockIdx.x * 4 + w;   // grid 250 -> n in [0,1000)
    float ac0 = 0.f, ac1 = 0.f, ab[8] = {}, ap[6] = {};
    const float* xr = x2 + (size_t)n * 1024;
    for (int kk = 0; kk < 16; kk++) {
        int k = kk * 64 + l;
        float xv = xr[k];
        ac0 += xv * wc[k];
        ac1 += xv * wc[1024 + k];
        #pragma unroll
        for (int o = 0; o < 8; o++) ab[o] += xv * wb[o * 1024 + k];
        #pragma unroll
        for (int o = 0; o < 6; o++) ap[o] += xv * wp[o * 1024 + k];
    }
    ac0 = wred(ac0); ac1 = wred(ac1);
    #pragma unroll
    for (int o = 0; o < 8; o++) ab[o] = wred(ab[o]);
    #pragma unroll
    for (int o = 0; o < 6; o++) ap[o] = wred(ap[o]);
    if (l == 0) {
        float l0 = ac0 + bc[0], l1 = ac1 + bc[1];
        out[n * 2] = l0; out[n * 2 + 1] = l1;
        float m = fmaxf(l0, l1);
        float e0 = expf(l0 - m), e1 = expf(l1 - m);
        float inv = 1.0f / (e0 + e1);
        out[2000 + n * 2] = e0 * inv; out[2000 + n * 2 + 1] = e1 * inv;
        #pragma unroll
        for (int o = 0; o < 8; o++) out[4000 + n * 8 + o] = ab[o] + bb[o];
        #pragma unroll
        for (int o = 0; o < 6; o++) out[12000 + n * 6 + o] = ap[o] + bp[o];
    }
}

extern "C" void kernel_launch(void* const* d_in, const int* in_sizes, int n_in,
                              void* d_out, int out_size, void* d_ws, size_t ws_size,
                              hipStream_t stream) {
    const float* p2      = (const float*)d_in[0];
    const float* p3      = (const float*)d_in[1];
    const float* p4      = (const float*)d_in[2];
    const float* p5      = (const float*)d_in[3];
    const float* rois    = (const float*)d_in[4];
    const float* ranges  = (const float*)d_in[5];
    const float* conv1_w = (const float*)d_in[6];
    const float* conv1_b = (const float*)d_in[7];
    const float* bn1_g   = (const float*)d_in[8];
    const float* bn1_b   = (const float*)d_in[9];
    const float* bn1_m   = (const float*)d_in[10];
    const float* bn1_v   = (const float*)d_in[11];
    const float* conv2_w = (const float*)d_in[12];
    const float* conv2_b = (const float*)d_in[13];
    const float* bn2_g   = (const float*)d_in[14];
    const float* bn2_b   = (const float*)d_in[15];
    const float* bn2_m   = (const float*)d_in[16];
    const float* bn2_v   = (const float*)d_in[17];
    const float* wc      = (const float*)d_in[18];
    const float* bc      = (const float*)d_in[19];
    const float* wb      = (const float*)d_in[20];
    const float* bb      = (const float*)d_in[21];
    const float* wp      = (const float*)d_in[22];
    const float* bp      = (const float*)d_in[23];

    char* ws = (char*)d_ws;
    float* tab  = (float*)(ws + OFF_TAB);
    bf16*  A    = (bf16*)(ws + OFF_A);
    bf16*  W1b  = (bf16*)(ws + OFF_W1);
    bf16*  W2b  = (bf16*)(ws + OFF_W2);
    float* part = (float*)(ws + OFF_PART);
    bf16*  x1b  = (bf16*)(ws + OFF_X1B);
    float* x2   = (float*)(ws + OFF_X2);
    float* out  = (float*)d_out;

    k_roi_setup<<<4, 256, 0, stream>>>(rois, tab);
    k_convert<<<16704, 256, 0, stream>>>(conv1_w, conv2_w, W1b, W2b);
    k_crop<<<62720, 256, 0, stream>>>(p2, p3, p4, p5, ranges, tab, out + 18000, A);
    k_gemm<<<dim3(8, 8, 8), 256, 0, stream>>>(A, W1b, part, 15680, 30, 5);
    k_reduce1<<<1024, 256, 0, stream>>>(part, conv1_b, bn1_g, bn1_b, bn1_m, bn1_v, x1b);
    k_gemm<<<dim3(8, 8, 4), 256, 0, stream>>>(x1b, W2b, part, 1024, 4, 0);
    k_reduce2<<<1024, 256, 0, stream>>>(part, conv2_b, bn2_g, bn2_b, bn2_m, bn2_v, x2);
    k_heads<<<250, 256, 0, stream>>>(x2, wc, bc, wb, bb, wp, bp, out);
}

// Round 2
// 176.339 us; speedup vs baseline: 1.2175x; 1.2175x over previous
//
#include <hip/hip_runtime.h>
#include <hip/hip_bf16.h>
#include <stdint.h>

typedef __bf16 bf16;
typedef __bf16 bf16x8 __attribute__((ext_vector_type(8)));
typedef __bf16 bf16x4 __attribute__((ext_vector_type(4)));
typedef __bf16 bf16x2 __attribute__((ext_vector_type(2)));
typedef float f32x4 __attribute__((ext_vector_type(4)));
typedef float f32x2 __attribute__((ext_vector_type(2)));
typedef int i32x4 __attribute__((ext_vector_type(4)));

#define GAS __attribute__((address_space(1)))
#define LAS __attribute__((address_space(3)))

#define NROIS 1000
#define DEPTH 256
#define CIN 320
#define KDIM 15680      // 320*49
#define TABS 120

// NHWC offsets (floats, within T region)
#define T_P2 0
#define T_P3 6553600
#define T_P4 8192000
#define T_P5 8601600
#define T_RNG 8704000
#define T_FLOATS 10342400

// ws byte offsets (aliased regions; all uses stream-ordered)
#define OFF_TAB  0ULL
#define OFF_A    524288ULL                 // 32,112,640 B
#define OFF_T    32636928ULL               // NHWC 41,369,600 B (dead after crop)
#define OFF_W1   32636928ULL               // alias NHWC (convert runs after crop)
#define OFF_W2   64749568ULL
#define OFF_PART 66846720ULL               // 33,554,432 B
#define OFF_X1B  524288ULL                 // alias A (after gemm1)
#define OFF_X2   2621440ULL                // 4 MB

// ---------------- per-ROI interpolation tables ----------------
__global__ void k_roi_setup(const float* __restrict__ rois, float* __restrict__ tab) {
    int n = blockIdx.x * 256 + threadIdx.x;
    if (n >= NROIS) return;
    float y1 = rois[n*4+0], x1 = rois[n*4+1], y2 = rois[n*4+2], x2 = rois[n*4+3];
    float h = __fsub_rn(y2, y1), w = __fsub_rn(x2, x1);
    float rl = 4.0f + logf(sqrtf(h * w) / (224.0f / 640.0f)) / logf(2.0f);
    int lvl = (int)rintf(rl);
    lvl = min(5, max(2, lvl));
    float* t = tab + (size_t)n * TABS;
    t[112] = (float)lvl;
    int Hs0 = 160 >> (lvl - 2);
    for (int g = 0; g < 2; g++) {
        int H = g ? 160 : Hs0;
        float* tg = t + g * 56;
        float fH = (float)(H - 1);
        float a = __fmul_rn(y1, fH);
        float s = __fdiv_rn(__fmul_rn(h, fH), 6.0f);
        for (int i = 0; i < 7; i++) {
            float iny = __fadd_rn(a, __fmul_rn((float)i, s));
            float tp = floorf(iny), bt = ceilf(iny);
            tg[i]      = (float)min(H-1, max(0, (int)tp));
            tg[7 + i]  = (float)min(H-1, max(0, (int)bt));
            tg[14 + i] = iny - tp;
            tg[21 + i] = (iny >= 0.0f && iny <= fH) ? 1.0f : 0.0f;
        }
        a = __fmul_rn(x1, fH);
        s = __fdiv_rn(__fmul_rn(w, fH), 6.0f);
        for (int j = 0; j < 7; j++) {
            float inx = __fadd_rn(a, __fmul_rn((float)j, s));
            float lf = floorf(inx), rt = ceilf(inx);
            tg[28 + j] = (float)min(H-1, max(0, (int)lf));
            tg[35 + j] = (float)min(H-1, max(0, (int)rt));
            tg[42 + j] = inx - lf;
            tg[49 + j] = (inx >= 0.0f && inx <= fH) ? 1.0f : 0.0f;
        }
    }
}

// ---------------- CHW -> HWC transpose (all 5 tensors in one grid) ----------------
__global__ __launch_bounds__(256) void k_transpose(const float* __restrict__ p2, const float* __restrict__ p3,
                                                   const float* __restrict__ p4, const float* __restrict__ p5,
                                                   const float* __restrict__ rng, float* __restrict__ T) {
    __shared__ float tile[64][65];
    int bid = blockIdx.x, t = threadIdx.x;
    const float* src; float* dst; int C, X, loc;
    if (bid < 1600)      { src = p2;  dst = T + T_P2;  C = 256; X = 25600; loc = bid; }
    else if (bid < 2000) { src = p3;  dst = T + T_P3;  C = 256; X = 6400;  loc = bid - 1600; }
    else if (bid < 2100) { src = p4;  dst = T + T_P4;  C = 256; X = 1600;  loc = bid - 2000; }
    else if (bid < 2128) { src = p5;  dst = T + T_P5;  C = 256; X = 400;   loc = bid - 2100; }
    else                 { src = rng; dst = T + T_RNG; C = 64;  X = 25600; loc = bid - 2128; }
    int xtiles = (X + 63) >> 6;
    int xt = loc % xtiles, ct = loc / xtiles;
    int x0 = xt << 6, c0 = ct << 6;
    #pragma unroll
    for (int r = 0; r < 16; r++) {
        int lin = r * 256 + t;
        int lc = lin >> 6, lx = lin & 63;
        int x = x0 + lx;
        tile[lc][lx] = (x < X) ? src[(size_t)(c0 + lc) * X + x] : 0.0f;
    }
    __syncthreads();
    #pragma unroll
    for (int r = 0; r < 16; r++) {
        int lin = r * 256 + t;
        int lxx = lin >> 6, lcc = lin & 63;
        int x = x0 + lxx;
        if (x < X) dst[(size_t)x * C + c0 + lcc] = tile[lcc][lxx];
    }
}

// ---------------- crop_and_resize from NHWC: coalesced taps, LDS-staged output ----------------
#define RES_S 329
__global__ __launch_bounds__(256) void k_crop2(const float* __restrict__ T, const float* __restrict__ tab,
                                               float* __restrict__ out_rf, bf16* __restrict__ A) {
    int n = blockIdx.x, t = threadIdx.x;
    if (n >= NROIS) {                 // zero-pad A rows 1000..1023
        i32x4* row = (i32x4*)(A + (size_t)n * KDIM);
        for (int i = t; i < KDIM * 2 / 16; i += 256) row[i] = i32x4{0,0,0,0};
        return;
    }
    __shared__ float res[49 * RES_S];     // [pos][c], stride 329 (odd -> conflict-free readback)
    __shared__ float tl_[TABS];
    if (t < TABS) tl_[t] = tab[(size_t)n * TABS + t];
    __syncthreads();
    int lvl = (int)tl_[112];
    int H = 160 >> (lvl - 2);
    int toff = (lvl == 2) ? T_P2 : (lvl == 3) ? T_P3 : (lvl == 4) ? T_P4 : T_P5;
    const float* F = T + toff;

    // level channels: lanes = 64 channel-quads, wave id = pos offset (uniform pos per wave)
    {
        int q = t & 63, pl = t >> 6, c4 = q * 4;
        for (int g = 0; g < 13; g++) {
            int pos = g * 4 + pl;
            if (pos < 49) {
                int i = pos / 7, j = pos % 7;
                int ti = (int)tl_[i],      bi = (int)tl_[7 + i];
                int li = (int)tl_[28 + j], ri = (int)tl_[35 + j];
                float ly = tl_[14 + i], lx = tl_[42 + j];
                float valid = tl_[21 + i] * tl_[49 + j];
                f32x4 vtl = *(const f32x4*)(F + (size_t)(ti * H + li) * 256 + c4);
                f32x4 vtr = *(const f32x4*)(F + (size_t)(ti * H + ri) * 256 + c4);
                f32x4 vbl = *(const f32x4*)(F + (size_t)(bi * H + li) * 256 + c4);
                f32x4 vbr = *(const f32x4*)(F + (size_t)(bi * H + ri) * 256 + c4);
                f32x4 top = vtl + (vtr - vtl) * lx;
                f32x4 bot = vbl + (vbr - vbl) * lx;
                f32x4 v = top + (bot - top) * ly;
                if (valid == 0.0f) v = f32x4{0.f,0.f,0.f,0.f};
                *(f32x4*)(&res[pos * RES_S + c4]) = v;
            }
        }
    }
    // range channels (64): 16 lanes of float4 per pos, 16 pos per 256 threads
    {
        int q = t & 15, pl = t >> 4, c4 = q * 4;
        const float* R = T + T_RNG;
        for (int g = 0; g < 4; g++) {
            int pos = g * 16 + pl;
            if (pos < 49) {
                int i = pos / 7, j = pos % 7;
                int ti = (int)tl_[56 + i], bi = (int)tl_[63 + i];
                int li = (int)tl_[84 + j], ri = (int)tl_[91 + j];
                float ly = tl_[70 + i], lx = tl_[98 + j];
                float valid = tl_[77 + i] * tl_[105 + j];
                f32x4 vtl = *(const f32x4*)(R + (size_t)(ti * 160 + li) * 64 + c4);
                f32x4 vtr = *(const f32x4*)(R + (size_t)(ti * 160 + ri) * 64 + c4);
                f32x4 vbl = *(const f32x4*)(R + (size_t)(bi * 160 + li) * 64 + c4);
                f32x4 vbr = *(const f32x4*)(R + (size_t)(bi * 160 + ri) * 64 + c4);
                f32x4 top = vtl + (vtr - vtl) * lx;
                f32x4 bot = vbl + (vbr - vbl) * lx;
                f32x4 v = top + (bot - top) * ly;
                if (valid == 0.0f) v = f32x4{0.f,0.f,0.f,0.f};
                *(f32x4*)(&res[pos * RES_S + 256 + c4]) = v;
            }
        }
    }
    __syncthreads();
    // linear coalesced write-out: out_rf f32 + A bf16, element order i = c*49+pos
    size_t ob = (size_t)n * KDIM;
    for (int k = 0; k < 31; k++) {
        int i2 = (k * 256 + t) * 2;
        if (i2 < KDIM) {
            float e0 = res[(i2 % 49) * RES_S + i2 / 49];
            int i3 = i2 + 1;
            float e1 = res[(i3 % 49) * RES_S + i3 / 49];
            *(f32x2*)(out_rf + ob + i2) = f32x2{e0, e1};
            bf16x2 b2; b2[0] = (bf16)e0; b2[1] = (bf16)e1;
            *(bf16x2*)(A + ob + i2) = b2;
        }
    }
}

// ---------------- weight f32 -> bf16 convert ----------------
__global__ void k_convert(const float* __restrict__ w1, const float* __restrict__ w2,
                          bf16* __restrict__ W1b, bf16* __restrict__ W2b) {
    int idx = blockIdx.x * 256 + threadIdx.x;
    const int n1 = 16056320 / 4;
    f32x4 v; bf16* dst;
    if (idx < n1) { v = ((const f32x4*)w1)[idx]; dst = W1b + (size_t)idx * 4; }
    else { int k = idx - n1; v = ((const f32x4*)w2)[k]; dst = W2b + (size_t)k * 4; }
    bf16x4 o;
    o[0] = (bf16)v[0]; o[1] = (bf16)v[1]; o[2] = (bf16)v[2]; o[3] = (bf16)v[3];
    *(bf16x4*)dst = o;
}

// ---------------- bf16 MFMA GEMM, C = A(MxK) * B(NxK)^T, split-K partials ----------------
__global__ __launch_bounds__(256) void k_gemm(const bf16* __restrict__ A, const bf16* __restrict__ B,
                                              float* __restrict__ part, int K,
                                              int steps_base, int steps_rem) {
    __shared__ bf16 sA[128 * 64];
    __shared__ bf16 sB[128 * 64];
    int tid = threadIdx.x;
    int l = tid & 63, w = tid >> 6;
    int tm = blockIdx.x * 128, tn = blockIdx.y * 128;
    int z = (int)blockIdx.z;
    int s0 = z * steps_base + min(z, steps_rem);
    int ns = steps_base + (z < steps_rem ? 1 : 0);
    f32x4 acc[4][4] = {};
    int rw = w * 32;
    int lr8 = l >> 3, lc8 = (l & 7) << 3;
    const bf16* Abase = A + (size_t)(tm + rw + lr8) * K + lc8;
    const bf16* Bbase = B + (size_t)(tn + rw + lr8) * K + lc8;
    int lr = l & 15, lh = l >> 4;
    int wm = (w >> 1) * 64, wn = (w & 1) * 64;

    for (int t = s0; t < s0 + ns; t++) {
        int kc = t * 64;
        #pragma unroll
        for (int q = 0; q < 4; q++) {
            __builtin_amdgcn_global_load_lds((const GAS void*)(Abase + (size_t)q * 8 * K + kc),
                                             (LAS void*)(sA + (rw + q * 8) * 64), 16, 0, 0);
            __builtin_amdgcn_global_load_lds((const GAS void*)(Bbase + (size_t)q * 8 * K + kc),
                                             (LAS void*)(sB + (rw + q * 8) * 64), 16, 0, 0);
        }
        __syncthreads();
        #pragma unroll
        for (int ks2 = 0; ks2 < 2; ks2++) {
            int kb = ks2 * 32 + lh * 8;
            bf16x8 af[4], bfr[4];
            #pragma unroll
            for (int mi = 0; mi < 4; mi++) af[mi] = *(const bf16x8*)(sA + (wm + mi * 16 + lr) * 64 + kb);
            #pragma unroll
            for (int ni = 0; ni < 4; ni++) bfr[ni] = *(const bf16x8*)(sB + (wn + ni * 16 + lr) * 64 + kb);
            #pragma unroll
            for (int mi = 0; mi < 4; mi++)
                #pragma unroll
                for (int ni = 0; ni < 4; ni++)
                    acc[mi][ni] = __builtin_amdgcn_mfma_f32_16x16x32_bf16(af[mi], bfr[ni], acc[mi][ni], 0, 0, 0);
        }
        __syncthreads();
    }
    float* pc = part + ((size_t)z << 20);
    #pragma unroll
    for (int mi = 0; mi < 4; mi++)
        #pragma unroll
        for (int ni = 0; ni < 4; ni++)
            #pragma unroll
            for (int r = 0; r < 4; r++)
                pc[(size_t)(tm + wm + mi * 16 + lh * 4 + r) * 1024 + (tn + wn + ni * 16 + lr)] = acc[mi][ni][r];
}

// ---------------- reduce split-K + bias + BN + ReLU -> bf16 (x1) ----------------
__global__ void k_reduce1(const float* __restrict__ part, const float* __restrict__ bias,
                          const float* __restrict__ gam, const float* __restrict__ bet,
                          const float* __restrict__ mu, const float* __restrict__ var,
                          bf16* __restrict__ x1b) {
    int idx = blockIdx.x * 256 + threadIdx.x;
    int n = idx >> 8;
    int o = (idx & 255) << 2;
    f32x4 v = {};
    #pragma unroll
    for (int s = 0; s < 8; s++) v += *(const f32x4*)(part + ((size_t)s << 20) + (size_t)n * 1024 + o);
    f32x4 b4 = *(const f32x4*)(bias + o);
    f32x4 g4 = *(const f32x4*)(gam + o);
    f32x4 e4 = *(const f32x4*)(bet + o);
    f32x4 m4 = *(const f32x4*)(mu + o);
    f32x4 v4 = *(const f32x4*)(var + o);
    bf16x4 ov;
    #pragma unroll
    for (int e = 0; e < 4; e++) {
        float sc = g4[e] / sqrtf(v4[e] + 0.001f);
        float y = (v[e] + b4[e] - m4[e]) * sc + e4[e];
        y = fmaxf(y, 0.0f);
        if (n >= NROIS) y = 0.0f;
        ov[e] = (bf16)y;
    }
    *(bf16x4*)(x1b + (size_t)n * 1024 + o) = ov;
}

// ---------------- reduce split-K + bias + BN + ReLU -> f32 (x2) ----------------
__global__ void k_reduce2(const float* __restrict__ part, const float* __restrict__ bias,
                          const float* __restrict__ gam, const float* __restrict__ bet,
                          const float* __restrict__ mu, const float* __restrict__ var,
                          float* __restrict__ x2) {
    int idx = blockIdx.x * 256 + threadIdx.x;
    int n = idx >> 8;
    int o = (idx & 255) << 2;
    f32x4 v = {};
    #pragma unroll
    for (int s = 0; s < 4; s++) v += *(const f32x4*)(part + ((size_t)s << 20) + (size_t)n * 1024 + o);
    f32x4 b4 = *(const f32x4*)(bias + o);
    f32x4 g4 = *(const f32x4*)(gam + o);
    f32x4 e4 = *(const f32x4*)(bet + o);
    f32x4 m4 = *(const f32x4*)(mu + o);
    f32x4 v4 = *(const f32x4*)(var + o);
    f32x4 ov;
    #pragma unroll
    for (int e = 0; e < 4; e++) {
        float sc = g4[e] / sqrtf(v4[e] + 0.001f);
        float y = (v[e] + b4[e] - m4[e]) * sc + e4[e];
        ov[e] = fmaxf(y, 0.0f);
    }
    *(f32x4*)(x2 + (size_t)n * 1024 + o) = ov;
}

// ---------------- heads ----------------
__device__ __forceinline__ float wred(float v) {
    #pragma unroll
    for (int off = 32; off; off >>= 1) v += __shfl_xor(v, off);
    return v;
}

__global__ void k_heads(const float* __restrict__ x2,
                        const float* __restrict__ wc, const float* __restrict__ bc,
                        const float* __restrict__ wb, const float* __restrict__ bb,
                        const float* __restrict__ wp, const float* __restrict__ bp,
                        float* __restrict__ out) {
    int w = threadIdx.x >> 6, l = threadIdx.x & 63;
    int n = blockIdx.x * 4 + w;
    float ac0 = 0.f, ac1 = 0.f, ab[8] = {}, ap[6] = {};
    const float* xr = x2 + (size_t)n * 1024;
    for (int kk = 0; kk < 16; kk++) {
        int k = kk * 64 + l;
        float xv = xr[k];
        ac0 += xv * wc[k];
        ac1 += xv * wc[1024 + k];
        #pragma unroll
        for (int o = 0; o < 8; o++) ab[o] += xv * wb[o * 1024 + k];
        #pragma unroll
        for (int o = 0; o < 6; o++) ap[o] += xv * wp[o * 1024 + k];
    }
    ac0 = wred(ac0); ac1 = wred(ac1);
    #pragma unroll
    for (int o = 0; o < 8; o++) ab[o] = wred(ab[o]);
    #pragma unroll
    for (int o = 0; o < 6; o++) ap[o] = wred(ap[o]);
    if (l == 0) {
        float l0 = ac0 + bc[0], l1 = ac1 + bc[1];
        out[n * 2] = l0; out[n * 2 + 1] = l1;
        float m = fmaxf(l0, l1);
        float e0 = expf(l0 - m), e1 = expf(l1 - m);
        float inv = 1.0f / (e0 + e1);
        out[2000 + n * 2] = e0 * inv; out[2000 + n * 2 + 1] = e1 * inv;
        #pragma unroll
        for (int o = 0; o < 8; o++) out[4000 + n * 8 + o] = ab[o] + bb[o];
        #pragma unroll
        for (int o = 0; o < 6; o++) out[12000 + n * 6 + o] = ap[o] + bp[o];
    }
}

extern "C" void kernel_launch(void* const* d_in, const int* in_sizes, int n_in,
                              void* d_out, int out_size, void* d_ws, size_t ws_size,
                              hipStream_t stream) {
    const float* p2      = (const float*)d_in[0];
    const float* p3      = (const float*)d_in[1];
    const float* p4      = (const float*)d_in[2];
    const float* p5      = (const float*)d_in[3];
    const float* rois    = (const float*)d_in[4];
    const float* ranges  = (const float*)d_in[5];
    const float* conv1_w = (const float*)d_in[6];
    const float* conv1_b = (const float*)d_in[7];
    const float* bn1_g   = (const float*)d_in[8];
    const float* bn1_b   = (const float*)d_in[9];
    const float* bn1_m   = (const float*)d_in[10];
    const float* bn1_v   = (const float*)d_in[11];
    const float* conv2_w = (const float*)d_in[12];
    const float* conv2_b = (const float*)d_in[13];
    const float* bn2_g   = (const float*)d_in[14];
    const float* bn2_b   = (const float*)d_in[15];
    const float* bn2_m   = (const float*)d_in[16];
    const float* bn2_v   = (const float*)d_in[17];
    const float* wc      = (const float*)d_in[18];
    const float* bc      = (const float*)d_in[19];
    const float* wb      = (const float*)d_in[20];
    const float* bb      = (const float*)d_in[21];
    const float* wp      = (const float*)d_in[22];
    const float* bp      = (const float*)d_in[23];

    char* ws = (char*)d_ws;
    float* tab  = (float*)(ws + OFF_TAB);
    bf16*  A    = (bf16*)(ws + OFF_A);
    float* T    = (float*)(ws + OFF_T);
    bf16*  W1b  = (bf16*)(ws + OFF_W1);
    bf16*  W2b  = (bf16*)(ws + OFF_W2);
    float* part = (float*)(ws + OFF_PART);
    bf16*  x1b  = (bf16*)(ws + OFF_X1B);
    float* x2   = (float*)(ws + OFF_X2);
    float* out  = (float*)d_out;

    k_roi_setup<<<4, 256, 0, stream>>>(rois, tab);
    k_transpose<<<2528, 256, 0, stream>>>(p2, p3, p4, p5, ranges, T);
    k_crop2<<<1024, 256, 0, stream>>>(T, tab, out + 18000, A);
    k_convert<<<16704, 256, 0, stream>>>(conv1_w, conv2_w, W1b, W2b);
    k_gemm<<<dim3(8, 8, 8), 256, 0, stream>>>(A, W1b, part, 15680, 30, 5);
    k_reduce1<<<1024, 256, 0, stream>>>(part, conv1_b, bn1_g, bn1_b, bn1_m, bn1_v, x1b);
    k_gemm<<<dim3(8, 8, 4), 256, 0, stream>>>(x1b, W2b, part, 1024, 4, 0);
    k_reduce2<<<1024, 256, 0, stream>>>(part, conv2_b, bn2_g, bn2_b, bn2_m, bn2_v, x2);
    k_heads<<<250, 256, 0, stream>>>(x2, wc, bc, wb, bb, wp, bp, out);
}